// Round 1
// baseline (320.972 us; speedup 1.0000x reference)
//
#include <hip/hip_runtime.h>
#include <hip/hip_bf16.h>

// Problem constants (B=2, T=2048, C=1024, H=16, G=4, hd=64, KV=256, WINDOW=256)
#define TT 2048
#define CC 1024
#define KVD 256
#define QKVD 1536

typedef __bf16 bf16x8 __attribute__((ext_vector_type(8)));
typedef float f32x4 __attribute__((ext_vector_type(4)));

// ---------------- pack / convert kernels ----------------

__global__ __launch_bounds__(256) void k_convert_x(const float* __restrict__ x,
                                                   __hip_bfloat16* __restrict__ xbf) {
  size_t idx = ((size_t)blockIdx.x * 256 + threadIdx.x) * 4;
  float4 v = *(const float4*)(x + idx);
  xbf[idx + 0] = __float2bfloat16(v.x);
  xbf[idx + 1] = __float2bfloat16(v.y);
  xbf[idx + 2] = __float2bfloat16(v.z);
  xbf[idx + 3] = __float2bfloat16(v.w);
}

// dst[n][k] = W*(k, n) packed (Wq | Wk | Wv), bf16, n in [0,1536), k in [0,1024)
__global__ __launch_bounds__(256) void k_pack_qkv_wT(const float* __restrict__ Wq,
                                                     const float* __restrict__ Wk,
                                                     const float* __restrict__ Wv,
                                                     __hip_bfloat16* __restrict__ dst) {
  int n = blockIdx.x;
  int k = blockIdx.y * 256 + threadIdx.x;
  float v;
  if (n < 1024)       v = Wq[(size_t)k * 1024 + n];
  else if (n < 1280)  v = Wk[(size_t)k * 256 + (n - 1024)];
  else                v = Wv[(size_t)k * 256 + (n - 1280)];
  dst[(size_t)n * 1024 + k] = __float2bfloat16(v);
}

__global__ __launch_bounds__(256) void k_pack_wo_T(const float* __restrict__ Wo,
                                                   __hip_bfloat16* __restrict__ dst) {
  int n = blockIdx.x;
  int k = blockIdx.y * 256 + threadIdx.x;
  dst[(size_t)n * 1024 + k] = __float2bfloat16(Wo[(size_t)k * 1024 + n]);
}

__global__ __launch_bounds__(256) void k_pack_bias(const float* __restrict__ bq,
                                                   const float* __restrict__ bk,
                                                   const float* __restrict__ bv,
                                                   float* __restrict__ dst) {
  int i = blockIdx.x * 256 + threadIdx.x;
  if (i < 1024)      dst[i] = bq[i];
  else if (i < 1280) dst[i] = bk[i - 1024];
  else               dst[i] = bv[i - 1280];
}

// ---------------- bf16 MFMA GEMM: C[M][N] = A[M][K] * BT[N][K]^T + bias ----------------
// grid (N/128, M/128), 256 threads (4 waves, 2x2 of 64x64), BK=32.

template <bool OUT_BF16>
__global__ __launch_bounds__(256, 2) void k_gemm_bt(const __hip_bfloat16* __restrict__ A,
                                                    const __hip_bfloat16* __restrict__ BT,
                                                    const float* __restrict__ bias,
                                                    void* __restrict__ C,
                                                    int M, int N, int K) {
  __shared__ __hip_bfloat16 As[128][40];  // pad 32->40 (80B row stride) to spread banks
  __shared__ __hip_bfloat16 Bs[128][40];

  const int tid  = threadIdx.x;
  const int m0   = blockIdx.y * 128;
  const int n0   = blockIdx.x * 128;
  const int w    = tid >> 6;
  const int lane = tid & 63;
  const int quad = lane >> 4;
  const int l16  = lane & 15;
  const int wm   = (w >> 1) * 64;
  const int wn   = (w & 1) * 64;
  const int sr   = tid >> 1;        // staging row 0..127
  const int sc   = (tid & 1) * 16;  // 0 or 16

  f32x4 acc[4][4] = {};

  const int nk = K >> 5;
  for (int kt = 0; kt < nk; ++kt) {
    const int k0 = kt << 5;
    const __hip_bfloat16* ap = A + (size_t)(m0 + sr) * K + k0 + sc;
    const __hip_bfloat16* bp = BT + (size_t)(n0 + sr) * K + k0 + sc;
    uint4 a0 = *(const uint4*)ap;
    uint4 a1 = *(const uint4*)(ap + 8);
    uint4 b0 = *(const uint4*)bp;
    uint4 b1 = *(const uint4*)(bp + 8);
    *(uint4*)&As[sr][sc]     = a0;
    *(uint4*)&As[sr][sc + 8] = a1;
    *(uint4*)&Bs[sr][sc]     = b0;
    *(uint4*)&Bs[sr][sc + 8] = b1;
    __syncthreads();

    bf16x8 fa[4], fb[4];
#pragma unroll
    for (int i = 0; i < 4; ++i) {
      fa[i] = *(const bf16x8*)&As[wm + i * 16 + l16][quad * 8];
      fb[i] = *(const bf16x8*)&Bs[wn + i * 16 + l16][quad * 8];
    }
#pragma unroll
    for (int i = 0; i < 4; ++i)
#pragma unroll
      for (int j = 0; j < 4; ++j)
        acc[i][j] = __builtin_amdgcn_mfma_f32_16x16x32_bf16(fa[i], fb[j], acc[i][j], 0, 0, 0);
    __syncthreads();
  }

  // epilogue: C/D layout col=lane&15, row=quad*4+reg  [HW-verified]
#pragma unroll
  for (int j = 0; j < 4; ++j) {
    const int gn = n0 + wn + j * 16 + l16;
    const float bias_v = bias[gn];
#pragma unroll
    for (int i = 0; i < 4; ++i) {
      const int gmb = m0 + wm + i * 16 + quad * 4;
#pragma unroll
      for (int r = 0; r < 4; ++r) {
        const float v = acc[i][j][r] + bias_v;
        const size_t idx = (size_t)(gmb + r) * N + gn;
        if (OUT_BF16) ((__hip_bfloat16*)C)[idx] = __float2bfloat16(v);
        else          ((float*)C)[idx] = v;
      }
    }
  }
}

// ---------------- fp32 flash attention (GQA, sliding window 256) ----------------
// qkv: [B*T][1536] bf16 (Q | K | V), y: [B*T][1024] bf16 (b,t,h,d layout)
// grid (T/64, H, B), 256 threads. Block handles 64 queries for one (b,h).

__device__ __forceinline__ void load16_bf16(const __hip_bfloat16* p, float* o) {
  uint4 u0 = *(const uint4*)p;
  uint4 u1 = *(const uint4*)(p + 8);
  const __hip_bfloat16* h0 = (const __hip_bfloat16*)&u0;
  const __hip_bfloat16* h1 = (const __hip_bfloat16*)&u1;
#pragma unroll
  for (int i = 0; i < 8; ++i) {
    o[i] = (float)h0[i];
    o[8 + i] = (float)h1[i];
  }
}

__global__ __launch_bounds__(256) void k_attn(const __hip_bfloat16* __restrict__ qkv,
                                              __hip_bfloat16* __restrict__ y) {
  __shared__ float Qs[64][68];  // [q][d], pre-scaled by 1/8
  __shared__ float KT[64][68];  // [d][k]  (transposed for vectorized score loop)
  __shared__ float Vs[64][68];  // [k][d]
  __shared__ float SP[64][68];  // scores, then probabilities
  __shared__ float mrow[64], lrow[64], arow[64];

  const int t  = threadIdx.x;
  const int bx = blockIdx.x;  // q-tile
  const int h  = blockIdx.y;
  const int b  = blockIdx.z;
  const int g  = h >> 2;  // GQA group (repeat_interleave: heads 4g..4g+3 -> group g)
  const int i0 = bx * 64;

  const int sr = t >> 2;         // 0..63
  const int sc = (t & 3) * 16;   // 0,16,32,48

  // stage Q (scaled by 1/sqrt(64))
  {
    const __hip_bfloat16* qp = qkv + ((size_t)(b * TT + i0 + sr)) * QKVD + h * 64 + sc;
    float tq[16];
    load16_bf16(qp, tq);
#pragma unroll
    for (int u = 0; u < 16; ++u) Qs[sr][sc + u] = 0.125f * tq[u];
  }
  if (t < 64) { mrow[t] = -INFINITY; lrow[t] = 0.f; }

  const int qa = (t >> 3) * 2;  // 0,2,...,62
  const int k8 = (t & 7) * 8;   // 0..56 (k-offset for scores, d-offset for PV)
  float o0[8] = {}, o1[8] = {};

  const int c_lo = bx >= 4 ? bx - 4 : 0;
  for (int c = c_lo; c <= bx; ++c) {
    __syncthreads();  // covers Q/m/l init on first iter, PV reads on later iters
    // stage K chunk (transposed) and V chunk
    {
      const size_t rowbase = (size_t)(b * TT + c * 64 + sr) * QKVD;
      const __hip_bfloat16* kp = qkv + rowbase + 1024 + g * 64 + sc;
      const __hip_bfloat16* vp = qkv + rowbase + 1280 + g * 64 + sc;
      float tk[16], tv[16];
      load16_bf16(kp, tk);
      load16_bf16(vp, tv);
#pragma unroll
      for (int u = 0; u < 16; ++u) KT[sc + u][sr] = tk[u];
#pragma unroll
      for (int u = 0; u < 4; ++u) *(float4*)&Vs[sr][sc + u * 4] = *(const float4*)&tv[u * 4];
    }
    __syncthreads();

    // S = Q K^T : each thread computes S[qa..qa+1][k8..k8+7]
    {
      float s0[8] = {}, s1[8] = {};
#pragma unroll 8
      for (int d = 0; d < 64; ++d) {
        const float q0 = Qs[qa][d];
        const float q1 = Qs[qa + 1][d];
        const float4 ka = *(const float4*)&KT[d][k8];
        const float4 kb = *(const float4*)&KT[d][k8 + 4];
        const float kv[8] = {ka.x, ka.y, ka.z, ka.w, kb.x, kb.y, kb.z, kb.w};
#pragma unroll
        for (int u = 0; u < 8; ++u) {
          s0[u] += q0 * kv[u];
          s1[u] += q1 * kv[u];
        }
      }
      *(float4*)&SP[qa][k8]         = float4{s0[0], s0[1], s0[2], s0[3]};
      *(float4*)&SP[qa][k8 + 4]     = float4{s0[4], s0[5], s0[6], s0[7]};
      *(float4*)&SP[qa + 1][k8]     = float4{s1[0], s1[1], s1[2], s1[3]};
      *(float4*)&SP[qa + 1][k8 + 4] = float4{s1[4], s1[5], s1[6], s1[7]};
    }
    __syncthreads();

    // online softmax, one row per thread (wave 0 only)
    if (t < 64) {
      const int i = i0 + t;
      const int jc = c * 64;
      int klo = i - 256 - jc; if (klo < 0) klo = 0;
      int khi = i - jc;       if (khi > 63) khi = 63;
      const float mold = mrow[t];
      float mloc = mold;
      for (int kk = klo; kk <= khi; ++kk) mloc = fmaxf(mloc, SP[t][kk]);
      const float alpha = __expf(mold - mloc);
      float sum = 0.f;
      for (int kk = 0; kk < 64; ++kk) {
        float p = 0.f;
        if (kk >= klo && kk <= khi) { p = __expf(SP[t][kk] - mloc); sum += p; }
        SP[t][kk] = p;
      }
      lrow[t] = lrow[t] * alpha + sum;
      mrow[t] = mloc;
      arow[t] = alpha;
    }
    __syncthreads();

    // rescale O and accumulate P*V : thread owns O[qa..qa+1][k8..k8+7]
    {
      const float a0 = arow[qa];
      const float a1 = arow[qa + 1];
#pragma unroll
      for (int u = 0; u < 8; ++u) { o0[u] *= a0; o1[u] *= a1; }
#pragma unroll 4
      for (int kk = 0; kk < 64; ++kk) {
        const float p0 = SP[qa][kk];
        const float p1 = SP[qa + 1][kk];
        const float4 va = *(const float4*)&Vs[kk][k8];
        const float4 vb = *(const float4*)&Vs[kk][k8 + 4];
        const float vv[8] = {va.x, va.y, va.z, va.w, vb.x, vb.y, vb.z, vb.w};
#pragma unroll
        for (int u = 0; u < 8; ++u) {
          o0[u] += p0 * vv[u];
          o1[u] += p1 * vv[u];
        }
      }
    }
  }

  // epilogue: y[b, i, h*64+d] = O / l
  {
    const float inv0 = 1.f / lrow[qa];
    const float inv1 = 1.f / lrow[qa + 1];
    __hip_bfloat16* y0 = y + ((size_t)(b * TT + i0 + qa)) * CC + h * 64 + k8;
    __hip_bfloat16* y1 = y0 + CC;
#pragma unroll
    for (int u = 0; u < 8; ++u) {
      y0[u] = __float2bfloat16(o0[u] * inv0);
      y1[u] = __float2bfloat16(o1[u] * inv1);
    }
  }
}

// ---------------- launch ----------------

extern "C" void kernel_launch(void* const* d_in, const int* in_sizes, int n_in,
                              void* d_out, int out_size, void* d_ws, size_t ws_size,
                              hipStream_t stream) {
  const float* x  = (const float*)d_in[0];
  const float* Wq = (const float*)d_in[1];
  const float* bq = (const float*)d_in[2];
  const float* Wk = (const float*)d_in[3];
  const float* bk = (const float*)d_in[4];
  const float* Wv = (const float*)d_in[5];
  const float* bv = (const float*)d_in[6];
  const float* Wo = (const float*)d_in[7];
  const float* bo = (const float*)d_in[8];
  float* out = (float*)d_out;

  char* ws = (char*)d_ws;
  const size_t M = 2 * TT;  // 4096
  __hip_bfloat16* xbf    = (__hip_bfloat16*)(ws);                         // 8 MB
  __hip_bfloat16* qkv    = (__hip_bfloat16*)(ws + 8388608);               // 12 MB
  __hip_bfloat16* ybf    = (__hip_bfloat16*)(ws + 20971520);              // 8 MB
  __hip_bfloat16* wqkvT  = (__hip_bfloat16*)(ws + 29360128);              // 3 MB
  __hip_bfloat16* woT    = (__hip_bfloat16*)(ws + 32505856);              // 2 MB
  float*          bqkv   = (float*)(ws + 34603008);                       // 6 KB

  k_convert_x<<<4096, 256, 0, stream>>>(x, xbf);
  k_pack_qkv_wT<<<dim3(1536, 4), 256, 0, stream>>>(Wq, Wk, Wv, wqkvT);
  k_pack_wo_T<<<dim3(1024, 4), 256, 0, stream>>>(Wo, woT);
  k_pack_bias<<<6, 256, 0, stream>>>(bq, bk, bv, bqkv);

  // QKV projection: [4096 x 1024] * [1024 x 1536]
  k_gemm_bt<true><<<dim3(QKVD / 128, M / 128), 256, 0, stream>>>(xbf, wqkvT, bqkv, qkv,
                                                                 (int)M, QKVD, CC);
  // attention
  k_attn<<<dim3(TT / 64, 16, 2), 256, 0, stream>>>(qkv, ybf);

  // output projection: [4096 x 1024] * [1024 x 1024] -> fp32 out
  k_gemm_bt<false><<<dim3(CC / 128, M / 128), 256, 0, stream>>>(ybf, woT, bo, out,
                                                                (int)M, CC, CC);
}

// Round 2
// 200.929 us; speedup vs baseline: 1.5974x; 1.5974x over previous
//
#include <hip/hip_runtime.h>
#include <hip/hip_bf16.h>

// Problem constants (B=2, T=2048, C=1024, H=16, G=4, hd=64, KV=256, WINDOW=256)
#define TT 2048
#define CC 1024
#define KVD 256
#define QKVD 1536

typedef __bf16 bf16x8 __attribute__((ext_vector_type(8)));
typedef float f32x4 __attribute__((ext_vector_type(4)));

// ---------------- pack / convert kernels ----------------

__global__ __launch_bounds__(256) void k_convert_x(const float* __restrict__ x,
                                                   __hip_bfloat16* __restrict__ xbf) {
  size_t idx = ((size_t)blockIdx.x * 256 + threadIdx.x) * 4;
  float4 v = *(const float4*)(x + idx);
  xbf[idx + 0] = __float2bfloat16(v.x);
  xbf[idx + 1] = __float2bfloat16(v.y);
  xbf[idx + 2] = __float2bfloat16(v.z);
  xbf[idx + 3] = __float2bfloat16(v.w);
}

// Tile-transpose pack: dst[n][k] = W*(k,n) as bf16, coalesced both sides via LDS.
// grid (k-tiles=16, n-tiles=24). n-tile boundaries (1024,1280) are multiples of 64,
// so the source matrix is uniform per block.
__global__ __launch_bounds__(256) void k_pack_qkv_wT(const float* __restrict__ Wq,
                                                     const float* __restrict__ Wk,
                                                     const float* __restrict__ Wv,
                                                     __hip_bfloat16* __restrict__ dst) {
  __shared__ float tile[64][65];
  const int k0 = blockIdx.x * 64;
  const int n0 = blockIdx.y * 64;
  const float* src;
  int ncols;
  if (n0 < 1024)      { src = Wq; ncols = 1024; }
  else if (n0 < 1280) { src = Wk - 1024; ncols = 256; }   // col index n0+c-1024
  else                { src = Wv - 1280; ncols = 256; }
  const int rw = threadIdx.x >> 6;   // 0..3
  const int cl = threadIdx.x & 63;   // 0..63
#pragma unroll
  for (int i = 0; i < 16; ++i) {
    const int kr = rw + i * 4;
    tile[kr][cl] = src[(size_t)(k0 + kr) * ncols + n0 + cl];
  }
  __syncthreads();
#pragma unroll
  for (int i = 0; i < 16; ++i) {
    const int nr = rw + i * 4;
    dst[(size_t)(n0 + nr) * 1024 + k0 + cl] = __float2bfloat16(tile[cl][nr]);
  }
}

__global__ __launch_bounds__(256) void k_pack_wo_T(const float* __restrict__ Wo,
                                                   __hip_bfloat16* __restrict__ dst) {
  __shared__ float tile[64][65];
  const int k0 = blockIdx.x * 64;
  const int n0 = blockIdx.y * 64;
  const int rw = threadIdx.x >> 6;
  const int cl = threadIdx.x & 63;
#pragma unroll
  for (int i = 0; i < 16; ++i) {
    const int kr = rw + i * 4;
    tile[kr][cl] = Wo[(size_t)(k0 + kr) * 1024 + n0 + cl];
  }
  __syncthreads();
#pragma unroll
  for (int i = 0; i < 16; ++i) {
    const int nr = rw + i * 4;
    dst[(size_t)(n0 + nr) * 1024 + k0 + cl] = __float2bfloat16(tile[cl][nr]);
  }
}

__global__ __launch_bounds__(256) void k_pack_bias(const float* __restrict__ bq,
                                                   const float* __restrict__ bk,
                                                   const float* __restrict__ bv,
                                                   float* __restrict__ dst) {
  int i = blockIdx.x * 256 + threadIdx.x;
  if (i < 1024)      dst[i] = bq[i];
  else if (i < 1280) dst[i] = bk[i - 1024];
  else               dst[i] = bv[i - 1280];
}

// V transpose: vtg[(b*4+g)*64 + d][t] = qkv[(b*TT+t)*QKVD + 1280 + g*64 + d]
// grid (T/64, G, B)
__global__ __launch_bounds__(256) void k_vT(const __hip_bfloat16* __restrict__ qkv,
                                            __hip_bfloat16* __restrict__ vtg) {
  __shared__ __hip_bfloat16 tile[64][72];
  const int t0 = blockIdx.x * 64;
  const int g  = blockIdx.y;
  const int b  = blockIdx.z;
  const int r  = threadIdx.x >> 2;         // 0..63
  const int c  = (threadIdx.x & 3) * 16;   // 0,16,32,48
  const __hip_bfloat16* src = qkv + ((size_t)(b * TT + t0 + r)) * QKVD + 1280 + g * 64 + c;
  *(uint4*)&tile[r][c]     = *(const uint4*)src;
  *(uint4*)&tile[r][c + 8] = *(const uint4*)(src + 8);
  __syncthreads();
  __hip_bfloat16 tmp[16];
#pragma unroll
  for (int u = 0; u < 16; ++u) tmp[u] = tile[c + u][r];
  __hip_bfloat16* dst = vtg + ((size_t)((b * 4 + g) * 64 + r)) * TT + t0 + c;
  *(uint4*)dst       = *(const uint4*)tmp;
  *(uint4*)(dst + 8) = *(const uint4*)(tmp + 8);
}

// ---------------- bf16 MFMA GEMM: C[M][N] = A[M][K] * BT[N][K]^T + bias ----------------

template <bool OUT_BF16>
__global__ __launch_bounds__(256, 2) void k_gemm_bt(const __hip_bfloat16* __restrict__ A,
                                                    const __hip_bfloat16* __restrict__ BT,
                                                    const float* __restrict__ bias,
                                                    void* __restrict__ C,
                                                    int M, int N, int K) {
  __shared__ __hip_bfloat16 As[128][40];
  __shared__ __hip_bfloat16 Bs[128][40];

  const int tid  = threadIdx.x;
  const int m0   = blockIdx.y * 128;
  const int n0   = blockIdx.x * 128;
  const int w    = tid >> 6;
  const int lane = tid & 63;
  const int quad = lane >> 4;
  const int l16  = lane & 15;
  const int wm   = (w >> 1) * 64;
  const int wn   = (w & 1) * 64;
  const int sr   = tid >> 1;
  const int sc   = (tid & 1) * 16;

  f32x4 acc[4][4] = {};

  const int nk = K >> 5;
  for (int kt = 0; kt < nk; ++kt) {
    const int k0 = kt << 5;
    const __hip_bfloat16* ap = A + (size_t)(m0 + sr) * K + k0 + sc;
    const __hip_bfloat16* bp = BT + (size_t)(n0 + sr) * K + k0 + sc;
    uint4 a0 = *(const uint4*)ap;
    uint4 a1 = *(const uint4*)(ap + 8);
    uint4 b0 = *(const uint4*)bp;
    uint4 b1 = *(const uint4*)(bp + 8);
    *(uint4*)&As[sr][sc]     = a0;
    *(uint4*)&As[sr][sc + 8] = a1;
    *(uint4*)&Bs[sr][sc]     = b0;
    *(uint4*)&Bs[sr][sc + 8] = b1;
    __syncthreads();

    bf16x8 fa[4], fb[4];
#pragma unroll
    for (int i = 0; i < 4; ++i) {
      fa[i] = *(const bf16x8*)&As[wm + i * 16 + l16][quad * 8];
      fb[i] = *(const bf16x8*)&Bs[wn + i * 16 + l16][quad * 8];
    }
#pragma unroll
    for (int i = 0; i < 4; ++i)
#pragma unroll
      for (int j = 0; j < 4; ++j)
        acc[i][j] = __builtin_amdgcn_mfma_f32_16x16x32_bf16(fa[i], fb[j], acc[i][j], 0, 0, 0);
    __syncthreads();
  }

#pragma unroll
  for (int j = 0; j < 4; ++j) {
    const int gn = n0 + wn + j * 16 + l16;
    const float bias_v = bias[gn];
#pragma unroll
    for (int i = 0; i < 4; ++i) {
      const int gmb = m0 + wm + i * 16 + quad * 4;
#pragma unroll
      for (int r = 0; r < 4; ++r) {
        const float v = acc[i][j][r] + bias_v;
        const size_t idx = (size_t)(gmb + r) * N + gn;
        if (OUT_BF16) ((__hip_bfloat16*)C)[idx] = __float2bfloat16(v);
        else          ((float*)C)[idx] = v;
      }
    }
  }
}

// ---------------- MFMA flash attention (GQA, sliding window 256) ----------------
// Per-wave design, NO __syncthreads. Each wave owns 16 q rows for one (b,h).
// K frags direct from qkv (rows are [key][d] = BT layout for QK^T).
// V frags direct from vtg (rows are [d][key] = BT layout for PV).
// P (C-layout) -> A-layout via per-wave LDS tile.
// grid (T/64, H, B), 256 threads = 4 waves.

__global__ __launch_bounds__(256) void k_attn(const __hip_bfloat16* __restrict__ qkv,
                                              const __hip_bfloat16* __restrict__ vtg,
                                              __hip_bfloat16* __restrict__ y) {
  __shared__ __hip_bfloat16 Ps[4][16][72];  // per-wave P tile [q16][key64 + pad]

  const int t    = threadIdx.x;
  const int w    = t >> 6;
  const int lane = t & 63;
  const int quad = lane >> 4;
  const int l16  = lane & 15;
  const int bx   = blockIdx.x;
  const int h    = blockIdx.y;
  const int b    = blockIdx.z;
  const int g    = h >> 2;  // repeat_interleave: heads 4g..4g+3 -> group g
  const int i0   = bx * 64;
  const int qrow      = i0 + w * 16 + l16;       // A-frag row (m = l16)
  const int my_q_base = i0 + w * 16 + quad * 4;  // C-layout rows (quad*4 + r)

  // Q fragments (held across all chunks): A[m=l16][k=quad*8+j], ksteps d=0..31,32..63
  bf16x8 fq[2];
  {
    const __hip_bfloat16* qp = qkv + ((size_t)(b * TT + qrow)) * QKVD + h * 64 + quad * 8;
    fq[0] = *(const bf16x8*)qp;
    fq[1] = *(const bf16x8*)(qp + 32);
  }

  float m_r[4], l_r[4];
#pragma unroll
  for (int r = 0; r < 4; ++r) { m_r[r] = -INFINITY; l_r[r] = 0.f; }
  f32x4 o_acc[4] = {};  // jt: d-tile; element r -> O[quad*4+r][jt*16+l16]

  const int c_lo = bx >= 4 ? bx - 4 : 0;
  for (int c = c_lo; c <= bx; ++c) {
    const int jc = c * 64;

    // K fragments: BT[n=key=l16+16nt][k=d=quad*8+j+32ks]
    bf16x8 fk[4][2];
    const __hip_bfloat16* kbase =
        qkv + ((size_t)(b * TT + jc + l16)) * QKVD + 1024 + g * 64 + quad * 8;
#pragma unroll
    for (int nt = 0; nt < 4; ++nt) {
      fk[nt][0] = *(const bf16x8*)(kbase + (size_t)nt * 16 * QKVD);
      fk[nt][1] = *(const bf16x8*)(kbase + (size_t)nt * 16 * QKVD + 32);
    }
    // V fragments (prefetch): BT[n=d=l16+16jt][k=key=quad*8+j+32ks]
    bf16x8 fv[4][2];
    const __hip_bfloat16* vbase =
        vtg + ((size_t)((b * 4 + g) * 64 + l16)) * TT + jc + quad * 8;
#pragma unroll
    for (int jt = 0; jt < 4; ++jt) {
      fv[jt][0] = *(const bf16x8*)(vbase + (size_t)jt * 16 * TT);
      fv[jt][1] = *(const bf16x8*)(vbase + (size_t)jt * 16 * TT + 32);
    }

    // S = Q K^T  (16 q x 64 key per wave)
    f32x4 sacc[4] = {};
#pragma unroll
    for (int nt = 0; nt < 4; ++nt) {
      sacc[nt] = __builtin_amdgcn_mfma_f32_16x16x32_bf16(fq[0], fk[nt][0], sacc[nt], 0, 0, 0);
      sacc[nt] = __builtin_amdgcn_mfma_f32_16x16x32_bf16(fq[1], fk[nt][1], sacc[nt], 0, 0, 0);
    }

    // online softmax: each lane owns rows quad*4+r, cols l16+16nt
    float alpha[4];
#pragma unroll
    for (int r = 0; r < 4; ++r) {
      const int gi = my_q_base + r;
      const int lo = gi - 256;
      float s_r[4];
      float mx = -INFINITY;
#pragma unroll
      for (int nt = 0; nt < 4; ++nt) {
        const int key = jc + nt * 16 + l16;
        float s = sacc[nt][r] * 0.125f;  // 1/sqrt(64)
        s = (key <= gi && key >= lo) ? s : -INFINITY;
        s_r[nt] = s;
        mx = fmaxf(mx, s);
      }
#pragma unroll
      for (int d = 1; d < 16; d <<= 1) mx = fmaxf(mx, __shfl_xor(mx, d));
      const float mo = m_r[r];
      const float mn = fmaxf(mo, mx);  // finite: every chunk has >=1 valid key per row
      const float al = __expf(mo - mn);
      float sum = 0.f;
#pragma unroll
      for (int nt = 0; nt < 4; ++nt) {
        const float p = __expf(s_r[nt] - mn);
        sum += p;
        Ps[w][quad * 4 + r][nt * 16 + l16] = __float2bfloat16(p);
      }
#pragma unroll
      for (int d = 1; d < 16; d <<= 1) sum += __shfl_xor(sum, d);
      m_r[r] = mn;
      l_r[r] = l_r[r] * al + sum;
      alpha[r] = al;
    }

    // rescale O
#pragma unroll
    for (int jt = 0; jt < 4; ++jt)
#pragma unroll
      for (int r = 0; r < 4; ++r) o_acc[jt][r] *= alpha[r];

    // P A-frags (same wave wrote them; lgkmcnt ordering, no barrier needed)
    bf16x8 fp0 = *(const bf16x8*)&Ps[w][l16][quad * 8];
    bf16x8 fp1 = *(const bf16x8*)&Ps[w][l16][32 + quad * 8];

    // O += P V
#pragma unroll
    for (int jt = 0; jt < 4; ++jt) {
      o_acc[jt] = __builtin_amdgcn_mfma_f32_16x16x32_bf16(fp0, fv[jt][0], o_acc[jt], 0, 0, 0);
      o_acc[jt] = __builtin_amdgcn_mfma_f32_16x16x32_bf16(fp1, fv[jt][1], o_acc[jt], 0, 0, 0);
    }
  }

  // epilogue: y[b, i, h*64 + d] = O / l   (bf16)
#pragma unroll
  for (int r = 0; r < 4; ++r) {
    const float inv = 1.f / l_r[r];
    __hip_bfloat16* yp = y + ((size_t)(b * TT + my_q_base + r)) * CC + h * 64 + l16;
#pragma unroll
    for (int jt = 0; jt < 4; ++jt)
      yp[jt * 16] = __float2bfloat16(o_acc[jt][r] * inv);
  }
}

// ---------------- launch ----------------

extern "C" void kernel_launch(void* const* d_in, const int* in_sizes, int n_in,
                              void* d_out, int out_size, void* d_ws, size_t ws_size,
                              hipStream_t stream) {
  const float* x  = (const float*)d_in[0];
  const float* Wq = (const float*)d_in[1];
  const float* bq = (const float*)d_in[2];
  const float* Wk = (const float*)d_in[3];
  const float* bk = (const float*)d_in[4];
  const float* Wv = (const float*)d_in[5];
  const float* bv = (const float*)d_in[6];
  const float* Wo = (const float*)d_in[7];
  const float* bo = (const float*)d_in[8];
  float* out = (float*)d_out;

  char* ws = (char*)d_ws;
  const size_t M = 2 * TT;  // 4096
  __hip_bfloat16* xbf   = (__hip_bfloat16*)(ws);               // 8 MB
  __hip_bfloat16* qkv   = (__hip_bfloat16*)(ws + 8388608);     // 12 MB
  __hip_bfloat16* ybf   = (__hip_bfloat16*)(ws + 20971520);    // 8 MB
  __hip_bfloat16* wqkvT = (__hip_bfloat16*)(ws + 29360128);    // 3 MB
  __hip_bfloat16* woT   = (__hip_bfloat16*)(ws + 32505856);    // 2 MB
  float*          bqkv  = (float*)(ws + 34603008);             // 6 KB
  __hip_bfloat16* vtg   = (__hip_bfloat16*)(ws + 34609152);    // 2 MB

  k_convert_x<<<4096, 256, 0, stream>>>(x, xbf);
  k_pack_qkv_wT<<<dim3(16, 24), 256, 0, stream>>>(Wq, Wk, Wv, wqkvT);
  k_pack_wo_T<<<dim3(16, 16), 256, 0, stream>>>(Wo, woT);
  k_pack_bias<<<6, 256, 0, stream>>>(bq, bk, bv, bqkv);

  // QKV projection: [4096 x 1024] * [1024 x 1536]
  k_gemm_bt<true><<<dim3(QKVD / 128, M / 128), 256, 0, stream>>>(xbf, wqkvT, bqkv, qkv,
                                                                 (int)M, QKVD, CC);
  // V transpose for PV B-operand
  k_vT<<<dim3(TT / 64, 4, 2), 256, 0, stream>>>(qkv, vtg);

  // attention
  k_attn<<<dim3(TT / 64, 16, 2), 256, 0, stream>>>(qkv, vtg, ybf);

  // output projection: [4096 x 1024] * [1024 x 1024] -> fp32 out
  k_gemm_bt<false><<<dim3(CC / 128, M / 128), 256, 0, stream>>>(ybf, woT, bo, out,
                                                                (int)M, CC, CC);
}

// Round 3
// 167.912 us; speedup vs baseline: 1.9116x; 1.1966x over previous
//
#include <hip/hip_runtime.h>
#include <hip/hip_bf16.h>

// Problem constants (B=2, T=2048, C=1024, H=16, G=4, hd=64, KV=256, WINDOW=256)
#define TT 2048
#define CC 1024
#define KVD 256
#define QKVD 1536

typedef __bf16 bf16x8 __attribute__((ext_vector_type(8)));
typedef float f32x4 __attribute__((ext_vector_type(4)));

// async global->LDS, 16B per lane. LDS dest is wave-uniform base + lane*16 (HW rule).
__device__ __forceinline__ void gload_lds16(const __hip_bfloat16* g, __hip_bfloat16* l) {
  __builtin_amdgcn_global_load_lds(
      (const __attribute__((address_space(1))) unsigned int*)g,
      (__attribute__((address_space(3))) unsigned int*)l, 16, 0, 0);
}

// ---------------- pack / convert kernels ----------------

__global__ __launch_bounds__(256) void k_convert_x(const float* __restrict__ x,
                                                   __hip_bfloat16* __restrict__ xbf) {
  size_t idx = ((size_t)blockIdx.x * 256 + threadIdx.x) * 4;
  float4 v = *(const float4*)(x + idx);
  xbf[idx + 0] = __float2bfloat16(v.x);
  xbf[idx + 1] = __float2bfloat16(v.y);
  xbf[idx + 2] = __float2bfloat16(v.z);
  xbf[idx + 3] = __float2bfloat16(v.w);
}

// Merged weight pack: z=0 -> wqkvT (24 n-tiles), z=1 -> woT (16 n-tiles) + bias block.
// dst[n][k] = W(k,n) as bf16, LDS tile transpose, coalesced both sides.
__global__ __launch_bounds__(256) void k_pack_w(const float* __restrict__ Wq,
                                                const float* __restrict__ Wk,
                                                const float* __restrict__ Wv,
                                                const float* __restrict__ Wo,
                                                const float* __restrict__ bq,
                                                const float* __restrict__ bk,
                                                const float* __restrict__ bv,
                                                __hip_bfloat16* __restrict__ wqkvT,
                                                __hip_bfloat16* __restrict__ woT,
                                                float* __restrict__ bqkv) {
  if (blockIdx.z == 1 && blockIdx.y >= 16) {
    if (blockIdx.y == 16 && blockIdx.x == 0) {
      for (int i = threadIdx.x; i < 1536; i += 256) {
        float v;
        if (i < 1024)      v = bq[i];
        else if (i < 1280) v = bk[i - 1024];
        else               v = bv[i - 1280];
        bqkv[i] = v;
      }
    }
    return;
  }
  __shared__ float tile[64][65];
  const int k0 = blockIdx.x * 64;
  const int n0 = blockIdx.y * 64;
  const float* src;
  int ncols;
  __hip_bfloat16* dst;
  if (blockIdx.z == 0) {
    dst = wqkvT;
    if (n0 < 1024)      { src = Wq; ncols = 1024; }
    else if (n0 < 1280) { src = Wk - 1024; ncols = 256; }  // effective col = n-1024
    else                { src = Wv - 1280; ncols = 256; }
  } else {
    dst = woT; src = Wo; ncols = 1024;
  }
  const int rw = threadIdx.x >> 6;   // 0..3
  const int cl = threadIdx.x & 63;   // 0..63
#pragma unroll
  for (int i = 0; i < 16; ++i) {
    const int kr = rw + i * 4;
    tile[kr][cl] = src[(size_t)(k0 + kr) * ncols + n0 + cl];
  }
  __syncthreads();
#pragma unroll
  for (int i = 0; i < 16; ++i) {
    const int nr = rw + i * 4;
    dst[(size_t)(n0 + nr) * 1024 + k0 + cl] = __float2bfloat16(tile[cl][nr]);
  }
}

// V transpose: vtg[(b*4+g)*64 + d][t] = qkv[(b*TT+t)*QKVD + 1280 + g*64 + d]
__global__ __launch_bounds__(256) void k_vT(const __hip_bfloat16* __restrict__ qkv,
                                            __hip_bfloat16* __restrict__ vtg) {
  __shared__ __hip_bfloat16 tile[64][72];
  const int t0 = blockIdx.x * 64;
  const int g  = blockIdx.y;
  const int b  = blockIdx.z;
  const int r  = threadIdx.x >> 2;
  const int c  = (threadIdx.x & 3) * 16;
  const __hip_bfloat16* src = qkv + ((size_t)(b * TT + t0 + r)) * QKVD + 1280 + g * 64 + c;
  *(uint4*)&tile[r][c]     = *(const uint4*)src;
  *(uint4*)&tile[r][c + 8] = *(const uint4*)(src + 8);
  __syncthreads();
  __hip_bfloat16 tmp[16];
#pragma unroll
  for (int u = 0; u < 16; ++u) tmp[u] = tile[c + u][r];
  __hip_bfloat16* dst = vtg + ((size_t)((b * 4 + g) * 64 + r)) * TT + t0 + c;
  *(uint4*)dst       = *(const uint4*)tmp;
  *(uint4*)(dst + 8) = *(const uint4*)(tmp + 8);
}

// ---------------- bf16 MFMA GEMM: C[M][N] = A[M][K] * BT[N][K]^T + bias ----------------
// Tile 64(M) x 128(N), BK=64. 4 waves, each 32x64. global_load_lds width-16 staging
// with XOR-swizzled 16B chunks (chunk ^ (row&7)) so ds_read_b128 frag reads are
// 2-way-conflict-free on the unpadded direct-load layout.
// grid (N/128, M/64).

template <bool OUT_BF16>
__global__ __launch_bounds__(256, 4) void k_gemm_bt(const __hip_bfloat16* __restrict__ A,
                                                    const __hip_bfloat16* __restrict__ BT,
                                                    const float* __restrict__ bias,
                                                    void* __restrict__ C,
                                                    int M, int N, int K) {
  __shared__ __hip_bfloat16 As[64][64];    // 8 KB,  rows = 128B = 8x16B chunks
  __shared__ __hip_bfloat16 Bs[128][64];   // 16 KB

  const int tid  = threadIdx.x;
  const int m0   = blockIdx.y * 64;
  const int n0   = blockIdx.x * 128;
  const int w    = tid >> 6;
  const int lane = tid & 63;
  const int quad = lane >> 4;
  const int l16  = lane & 15;
  const int wm   = (w >> 1) * 32;
  const int wn   = (w & 1) * 64;

  // direct-load lane mapping: one inst = 8 rows x 128B; lane -> row lane>>3, LDS chunk lane&7.
  // LDS[row][c] holds global chunk c ^ (row&7).
  const int dl_r = lane >> 3;               // 0..7
  const int dl_c = (lane & 7) ^ dl_r;       // swizzled global 16B chunk

  const __hip_bfloat16* gA = A + (size_t)(m0 + w * 16 + dl_r) * K + dl_c * 8;
  const __hip_bfloat16* gB = BT + (size_t)(n0 + w * 32 + dl_r) * K + dl_c * 8;

  f32x4 acc[2][4] = {};

  const int nk = K >> 6;
  for (int kt = 0; kt < nk; ++kt) {
    const int k0 = kt << 6;
    gload_lds16(gA + k0,                 &As[w * 16][0]);
    gload_lds16(gA + k0 + (size_t)8 * K, &As[w * 16 + 8][0]);
    gload_lds16(gB + k0,                  &Bs[w * 32][0]);
    gload_lds16(gB + k0 + (size_t)8 * K,  &Bs[w * 32 + 8][0]);
    gload_lds16(gB + k0 + (size_t)16 * K, &Bs[w * 32 + 16][0]);
    gload_lds16(gB + k0 + (size_t)24 * K, &Bs[w * 32 + 24][0]);
    __syncthreads();  // vmcnt(0) drain before reads

#pragma unroll
    for (int ks = 0; ks < 2; ++ks) {
      const int cb = (ks << 2) + quad;  // global chunk wanted
      bf16x8 fa[2], fb[4];
#pragma unroll
      for (int i = 0; i < 2; ++i)
        fa[i] = *(const bf16x8*)&As[wm + i * 16 + l16][(cb ^ (l16 & 7)) << 3];
#pragma unroll
      for (int j = 0; j < 4; ++j)
        fb[j] = *(const bf16x8*)&Bs[wn + j * 16 + l16][(cb ^ (l16 & 7)) << 3];
#pragma unroll
      for (int i = 0; i < 2; ++i)
#pragma unroll
        for (int j = 0; j < 4; ++j)
          acc[i][j] = __builtin_amdgcn_mfma_f32_16x16x32_bf16(fa[i], fb[j], acc[i][j], 0, 0, 0);
    }
    __syncthreads();
  }

  // epilogue: C/D layout col=lane&15, row=quad*4+reg
#pragma unroll
  for (int j = 0; j < 4; ++j) {
    const int gn = n0 + wn + j * 16 + l16;
    const float bias_v = bias[gn];
#pragma unroll
    for (int i = 0; i < 2; ++i) {
      const int gmb = m0 + wm + i * 16 + quad * 4;
#pragma unroll
      for (int r = 0; r < 4; ++r) {
        const float v = acc[i][j][r] + bias_v;
        const size_t idx = (size_t)(gmb + r) * N + gn;
        if (OUT_BF16) ((__hip_bfloat16*)C)[idx] = __float2bfloat16(v);
        else          ((float*)C)[idx] = v;
      }
    }
  }
}

// ---------------- MFMA flash attention (GQA, sliding window 256) ----------------
// Per-wave, no __syncthreads. Wave owns 16 q rows for one (b,h).

__global__ __launch_bounds__(256) void k_attn(const __hip_bfloat16* __restrict__ qkv,
                                              const __hip_bfloat16* __restrict__ vtg,
                                              __hip_bfloat16* __restrict__ y) {
  __shared__ __hip_bfloat16 Ps[4][16][72];  // per-wave P tile

  const int t    = threadIdx.x;
  const int w    = t >> 6;
  const int lane = t & 63;
  const int quad = lane >> 4;
  const int l16  = lane & 15;
  const int bx   = blockIdx.x;
  const int h    = blockIdx.y;
  const int b    = blockIdx.z;
  const int g    = h >> 2;
  const int i0   = bx * 64;
  const int qrow      = i0 + w * 16 + l16;
  const int my_q_base = i0 + w * 16 + quad * 4;

  bf16x8 fq[2];
  {
    const __hip_bfloat16* qp = qkv + ((size_t)(b * TT + qrow)) * QKVD + h * 64 + quad * 8;
    fq[0] = *(const bf16x8*)qp;
    fq[1] = *(const bf16x8*)(qp + 32);
  }

  float m_r[4], l_r[4];
#pragma unroll
  for (int r = 0; r < 4; ++r) { m_r[r] = -INFINITY; l_r[r] = 0.f; }
  f32x4 o_acc[4] = {};

  const int c_lo = bx >= 4 ? bx - 4 : 0;
  for (int c = c_lo; c <= bx; ++c) {
    const int jc = c * 64;

    bf16x8 fk[4][2];
    const __hip_bfloat16* kbase =
        qkv + ((size_t)(b * TT + jc + l16)) * QKVD + 1024 + g * 64 + quad * 8;
#pragma unroll
    for (int nt = 0; nt < 4; ++nt) {
      fk[nt][0] = *(const bf16x8*)(kbase + (size_t)nt * 16 * QKVD);
      fk[nt][1] = *(const bf16x8*)(kbase + (size_t)nt * 16 * QKVD + 32);
    }
    bf16x8 fv[4][2];
    const __hip_bfloat16* vbase =
        vtg + ((size_t)((b * 4 + g) * 64 + l16)) * TT + jc + quad * 8;
#pragma unroll
    for (int jt = 0; jt < 4; ++jt) {
      fv[jt][0] = *(const bf16x8*)(vbase + (size_t)jt * 16 * TT);
      fv[jt][1] = *(const bf16x8*)(vbase + (size_t)jt * 16 * TT + 32);
    }

    f32x4 sacc[4] = {};
#pragma unroll
    for (int nt = 0; nt < 4; ++nt) {
      sacc[nt] = __builtin_amdgcn_mfma_f32_16x16x32_bf16(fq[0], fk[nt][0], sacc[nt], 0, 0, 0);
      sacc[nt] = __builtin_amdgcn_mfma_f32_16x16x32_bf16(fq[1], fk[nt][1], sacc[nt], 0, 0, 0);
    }

    float alpha[4];
#pragma unroll
    for (int r = 0; r < 4; ++r) {
      const int gi = my_q_base + r;
      const int lo = gi - 256;
      float s_r[4];
      float mx = -INFINITY;
#pragma unroll
      for (int nt = 0; nt < 4; ++nt) {
        const int key = jc + nt * 16 + l16;
        float s = sacc[nt][r] * 0.125f;
        s = (key <= gi && key >= lo) ? s : -INFINITY;
        s_r[nt] = s;
        mx = fmaxf(mx, s);
      }
#pragma unroll
      for (int d = 1; d < 16; d <<= 1) mx = fmaxf(mx, __shfl_xor(mx, d));
      const float mo = m_r[r];
      const float mn = fmaxf(mo, mx);
      const float al = __expf(mo - mn);
      float sum = 0.f;
#pragma unroll
      for (int nt = 0; nt < 4; ++nt) {
        const float p = __expf(s_r[nt] - mn);
        sum += p;
        Ps[w][quad * 4 + r][nt * 16 + l16] = __float2bfloat16(p);
      }
#pragma unroll
      for (int d = 1; d < 16; d <<= 1) sum += __shfl_xor(sum, d);
      m_r[r] = mn;
      l_r[r] = l_r[r] * al + sum;
      alpha[r] = al;
    }

#pragma unroll
    for (int jt = 0; jt < 4; ++jt)
#pragma unroll
      for (int r = 0; r < 4; ++r) o_acc[jt][r] *= alpha[r];

    bf16x8 fp0 = *(const bf16x8*)&Ps[w][l16][quad * 8];
    bf16x8 fp1 = *(const bf16x8*)&Ps[w][l16][32 + quad * 8];

#pragma unroll
    for (int jt = 0; jt < 4; ++jt) {
      o_acc[jt] = __builtin_amdgcn_mfma_f32_16x16x32_bf16(fp0, fv[jt][0], o_acc[jt], 0, 0, 0);
      o_acc[jt] = __builtin_amdgcn_mfma_f32_16x16x32_bf16(fp1, fv[jt][1], o_acc[jt], 0, 0, 0);
    }
  }

#pragma unroll
  for (int r = 0; r < 4; ++r) {
    const float inv = 1.f / l_r[r];
    __hip_bfloat16* yp = y + ((size_t)(b * TT + my_q_base + r)) * CC + h * 64 + l16;
#pragma unroll
    for (int jt = 0; jt < 4; ++jt)
      yp[jt * 16] = __float2bfloat16(o_acc[jt][r] * inv);
  }
}

// ---------------- launch ----------------

extern "C" void kernel_launch(void* const* d_in, const int* in_sizes, int n_in,
                              void* d_out, int out_size, void* d_ws, size_t ws_size,
                              hipStream_t stream) {
  const float* x  = (const float*)d_in[0];
  const float* Wq = (const float*)d_in[1];
  const float* bq = (const float*)d_in[2];
  const float* Wk = (const float*)d_in[3];
  const float* bk = (const float*)d_in[4];
  const float* Wv = (const float*)d_in[5];
  const float* bv = (const float*)d_in[6];
  const float* Wo = (const float*)d_in[7];
  const float* bo = (const float*)d_in[8];
  float* out = (float*)d_out;

  char* ws = (char*)d_ws;
  const size_t M = 2 * TT;  // 4096
  __hip_bfloat16* xbf   = (__hip_bfloat16*)(ws);               // 8 MB
  __hip_bfloat16* qkv   = (__hip_bfloat16*)(ws + 8388608);     // 12 MB
  __hip_bfloat16* ybf   = (__hip_bfloat16*)(ws + 20971520);    // 8 MB
  __hip_bfloat16* wqkvT = (__hip_bfloat16*)(ws + 29360128);    // 3 MB
  __hip_bfloat16* woT   = (__hip_bfloat16*)(ws + 32505856);    // 2 MB
  float*          bqkv  = (float*)(ws + 34603008);             // 6 KB
  __hip_bfloat16* vtg   = (__hip_bfloat16*)(ws + 34609152);    // 2 MB

  k_convert_x<<<4096, 256, 0, stream>>>(x, xbf);
  k_pack_w<<<dim3(16, 24, 2), 256, 0, stream>>>(Wq, Wk, Wv, Wo, bq, bk, bv,
                                                wqkvT, woT, bqkv);

  // QKV projection: [4096 x 1024] * [1024 x 1536]   grid 12x64 = 768 blocks (3/CU)
  k_gemm_bt<true><<<dim3(QKVD / 128, M / 64), 256, 0, stream>>>(xbf, wqkvT, bqkv, qkv,
                                                                (int)M, QKVD, CC);
  // V transpose for PV B-operand
  k_vT<<<dim3(TT / 64, 4, 2), 256, 0, stream>>>(qkv, vtg);

  // attention
  k_attn<<<dim3(TT / 64, 16, 2), 256, 0, stream>>>(qkv, vtg, ybf);

  // output projection: [4096 x 1024] * [1024 x 1024] -> fp32   grid 8x64 = 512 blocks (2/CU)
  k_gemm_bt<false><<<dim3(CC / 128, M / 64), 256, 0, stream>>>(ybf, woT, bo, out,
                                                               (int)M, CC, CC);
}